// Round 1
// baseline (675.111 us; speedup 1.0000x reference)
//
#include <hip/hip_runtime.h>
#include <hip/hip_bf16.h>

#define IN_CH 512
#define OUT_CH 512
#define W_DIM 512
#define BATCH 16
#define HWDIM 64
#define PADW 66

static constexpr float CONV_COEF = 0.014731391274719739f; // 1/sqrt(9*512)
static constexpr float FC_COEF   = 0.044194173824159216f; // 1/sqrt(512)

typedef __bf16 bf16x8 __attribute__((ext_vector_type(8)));
typedef float  f32x4  __attribute__((ext_vector_type(4)));

typedef __attribute__((address_space(1))) void gvoid;
typedef __attribute__((address_space(3))) void lvoid;

__device__ __forceinline__ void async_cp16(const void* g, void* l) {
    __builtin_amdgcn_global_load_lds((gvoid*)g, (lvoid*)l, 16, 0, 0);
}

__device__ __forceinline__ ushort f2bf(float f) {
    union { float f; unsigned u; } un; un.f = f;
    unsigned u = un.u;
    return (ushort)((u + 0x7fffu + ((u >> 16) & 1u)) >> 16);
}

// s[b,i] = (wl[b,:]·fcw[:,i])*FC_COEF + fcb[i] + 1
__global__ void k_style(const float* __restrict__ wl, const float* __restrict__ fcw,
                        const float* __restrict__ fcb, float* __restrict__ s) {
    int b = blockIdx.x;
    int i = threadIdx.x;
    __shared__ float lw[W_DIM];
    lw[i] = wl[b * W_DIM + i];
    __syncthreads();
    float acc = 0.f;
#pragma unroll 8
    for (int j = 0; j < W_DIM; ++j) acc += lw[j] * fcw[(size_t)j * IN_CH + i];
    s[b * IN_CH + i] = acc * FC_COEF + fcb[i] + 1.0f;
}

// xs[b][h+1][w+1][c] = bf16(x[b,h,w,c] * s[b,c])   (padded layout, border pre-zeroed)
__global__ void k_xs(const float* __restrict__ x, const float* __restrict__ s,
                     ushort* __restrict__ xs) {
    int t = blockIdx.x * blockDim.x + threadIdx.x;  // one float4 per thread
    int pix = t >> 7;
    int c = (t & 127) << 2;
    int b = pix >> 12;
    int hw = pix & 4095;
    int h = hw >> 6, w = hw & 63;
    float4 xv = ((const float4*)x)[t];
    float4 sv = ((const float4*)(s + b * IN_CH))[t & 127];
    ushort4 o;
    o.x = f2bf(xv.x * sv.x);
    o.y = f2bf(xv.y * sv.y);
    o.z = f2bf(xv.z * sv.z);
    o.w = f2bf(xv.w * sv.w);
    size_t dst = (((size_t)(b * PADW + h + 1)) * PADW + (w + 1)) * IN_CH + c;
    *(ushort4*)(xs + dst) = o;
}

// wT[kk][out][in] = bf16(w[kk][in][out])   (tiled transpose)
__global__ void k_wt(const float* __restrict__ w, ushort* __restrict__ wT) {
    __shared__ float tile[32][33];
    int kk = blockIdx.z;
    const float* src = w + (size_t)kk * IN_CH * OUT_CH;
    ushort* dst = wT + (size_t)kk * IN_CH * OUT_CH;
    int i0 = blockIdx.y * 32;
    int o0 = blockIdx.x * 32;
    int tx = threadIdx.x, ty = threadIdx.y;
#pragma unroll
    for (int rr = 0; rr < 32; rr += 8)
        tile[ty + rr][tx] = src[(size_t)(i0 + ty + rr) * OUT_CH + o0 + tx];
    __syncthreads();
#pragma unroll
    for (int rr = 0; rr < 32; rr += 8)
        dst[(size_t)(o0 + ty + rr) * IN_CH + i0 + tx] = f2bf(tile[tx][ty + rr]);
}

// a2[in*512+out] = sum_kk w[kk][in][out]^2
__global__ void k_a2(const float* __restrict__ w, float* __restrict__ a2) {
    int n = blockIdx.x * blockDim.x + threadIdx.x;
    float sum = 0.f;
#pragma unroll
    for (int kk = 0; kk < 9; ++kk) {
        float v = w[(size_t)kk * (IN_CH * OUT_CH) + n];
        sum += v * v;
    }
    a2[n] = sum;
}

// dmod[b,o] = rsqrt(coef^2 * sum_in a2[in,o]*s[b,in]^2 + 1e-8)
__global__ void k_dmod(const float* __restrict__ s, const float* __restrict__ a2,
                       float* __restrict__ dmod) {
    int b = blockIdx.x, o = threadIdx.x;
    __shared__ float s2[IN_CH];
    float sv = s[b * IN_CH + o];
    s2[o] = sv * sv;
    __syncthreads();
    float acc = 0.f;
#pragma unroll 8
    for (int i = 0; i < IN_CH; ++i) acc += s2[i] * a2[(size_t)i * OUT_CH + o];
    dmod[b * OUT_CH + o] = rsqrtf(acc * CONV_COEF * CONV_COEF + 1e-8f);
}

// Implicit-GEMM conv: M=65536 (b,h,w), N=512 (out), K=9*512.
// Block tile 128x128, BK=32, 4 waves of 64x64 (4x4 frags, mfma 16x16x32 bf16).
__global__ __launch_bounds__(256) void k_conv(
    const ushort* __restrict__ xs, const ushort* __restrict__ wT,
    const float* __restrict__ dmod, const float* __restrict__ bias,
    float* __restrict__ out) {
    __shared__ ushort sA[128 * 32];
    __shared__ ushort sB[128 * 32];

    const int tid = threadIdx.x;
    const int wave = tid >> 6;
    const int lane = tid & 63;

    const int bid = blockIdx.x;
    const int nt = bid & 3;
    const int mt = bid >> 2;
    const int b  = mt >> 5;
    const int h0 = (mt & 31) << 1;   // two image rows per M-tile
    const int n0 = nt << 7;

    // ---- staging geometry: slot = it*256 + tid; row = slot>>2, pos = slot&3
    // stored global k-chunk at (row,pos) is pos ^ ((row>>1)&3)  [bank swizzle]
    const int mi = tid >> 2;     // 0..63: w-position (A) / n-offset (B)
    const int p  = tid & 3;
    const int k8 = p ^ ((mi >> 1) & 3);

    const ushort* gA0 = xs + (((size_t)(b * PADW + h0)) * PADW + mi) * IN_CH + k8 * 8;
    const ushort* gA1 = gA0 + (size_t)PADW * IN_CH;    // row h0+1 (slots 256..511)
    const ushort* gB0 = wT + ((size_t)(n0 + mi)) * IN_CH + k8 * 8;
    const ushort* gB1 = gB0 + (size_t)64 * IN_CH;

    ushort* dA0 = sA + wave * 512;          // wave-uniform LDS dest (lane*16B implicit)
    ushort* dA1 = sA + 2048 + wave * 512;
    ushort* dB0 = sB + wave * 512;
    ushort* dB1 = sB + 2048 + wave * 512;

    // ---- fragment read addresses
    const int r = lane & 15;
    const int q = lane >> 4;
    const int pq = q ^ ((r >> 1) & 3);      // de-swizzle
    const int wr = (wave & 1) << 6;
    const int wc = (wave >> 1) << 6;

    const ushort* aRd[4];
    const ushort* bRd[4];
#pragma unroll
    for (int f = 0; f < 4; ++f) {
        aRd[f] = sA + (wr + f * 16 + r) * 32 + pq * 8;
        bRd[f] = sB + (wc + f * 16 + r) * 32 + pq * 8;
    }

    f32x4 acc[4][4];
#pragma unroll
    for (int i = 0; i < 4; ++i)
#pragma unroll
        for (int j = 0; j < 4; ++j) {
            f32x4 z = {0.f, 0.f, 0.f, 0.f};
            acc[i][j] = z;
        }

    for (int kk = 0; kk < 9; ++kk) {
        const int aoff = ((kk / 3) * PADW + (kk % 3)) * IN_CH;  // (kh*66+kw)*512
        const int boff = kk * (IN_CH * OUT_CH);
        for (int c0 = 0; c0 < IN_CH; c0 += 32) {
            __syncthreads();   // prev compute done before LDS overwrite
            async_cp16(gA0 + aoff + c0, dA0);
            async_cp16(gA1 + aoff + c0, dA1);
            async_cp16(gB0 + boff + c0, dB0);
            async_cp16(gB1 + boff + c0, dB1);
            __syncthreads();   // drains vmcnt -> staged data visible
            bf16x8 av[4], bv[4];
#pragma unroll
            for (int f = 0; f < 4; ++f) av[f] = *(const bf16x8*)aRd[f];
#pragma unroll
            for (int f = 0; f < 4; ++f) bv[f] = *(const bf16x8*)bRd[f];
#pragma unroll
            for (int i = 0; i < 4; ++i)
#pragma unroll
                for (int j = 0; j < 4; ++j)
                    acc[i][j] = __builtin_amdgcn_mfma_f32_16x16x32_bf16(
                        av[i], bv[j], acc[i][j], 0, 0, 0);
        }
    }

    // epilogue: C/D layout col=lane&15 (n), row=(lane>>4)*4+reg (m)
#pragma unroll
    for (int j = 0; j < 4; ++j) {
        const int n = n0 + wc + j * 16 + r;
        const float scale = dmod[b * OUT_CH + n] * CONV_COEF;
        const float bv2 = bias[n];
#pragma unroll
        for (int i = 0; i < 4; ++i) {
#pragma unroll
            for (int e = 0; e < 4; ++e) {
                const int m = wr + i * 16 + q * 4 + e;
                const int h = h0 + (m >> 6);
                const int w = m & 63;
                out[(((size_t)(b * HWDIM + h)) * HWDIM + w) * OUT_CH + n] =
                    acc[i][j][e] * scale + bv2;
            }
        }
    }
}

extern "C" void kernel_launch(void* const* d_in, const int* in_sizes, int n_in,
                              void* d_out, int out_size, void* d_ws, size_t ws_size,
                              hipStream_t stream) {
    const float* x    = (const float*)d_in[0];
    const float* wl   = (const float*)d_in[1];
    const float* w    = (const float*)d_in[2];
    const float* bias = (const float*)d_in[3];
    const float* fcw  = (const float*)d_in[4];
    const float* fcb  = (const float*)d_in[5];
    float* out = (float*)d_out;

    char* ws = (char*)d_ws;
    const size_t XS_BYTES = (size_t)BATCH * PADW * PADW * IN_CH * 2;  // 71,368,704
    const size_t WT_BYTES = (size_t)9 * IN_CH * OUT_CH * 2;           //  4,718,592
    ushort* xs   = (ushort*)ws;
    ushort* wT   = (ushort*)(ws + XS_BYTES);
    float*  s    = (float*)(ws + XS_BYTES + WT_BYTES);
    float*  dmod = s + BATCH * IN_CH;
    float*  a2   = dmod + BATCH * OUT_CH;

    hipMemsetAsync(xs, 0, XS_BYTES, stream);  // zero halo
    k_style<<<BATCH, W_DIM, 0, stream>>>(wl, fcw, fcb, s);
    k_xs<<<(BATCH * HWDIM * HWDIM * IN_CH / 4) / 256, 256, 0, stream>>>(x, s, xs);
    k_wt<<<dim3(16, 16, 9), dim3(32, 8), 0, stream>>>(w, wT);
    k_a2<<<(IN_CH * OUT_CH) / 256, 256, 0, stream>>>(w, a2);
    k_dmod<<<BATCH, OUT_CH, 0, stream>>>(s, a2, dmod);
    k_conv<<<2048, 256, 0, stream>>>(xs, wT, dmod, bias, out);
}

// Round 2
// 571.421 us; speedup vs baseline: 1.1815x; 1.1815x over previous
//
#include <hip/hip_runtime.h>
#include <hip/hip_bf16.h>

#define IN_CH 512
#define OUT_CH 512
#define W_DIM 512
#define BATCH 16
#define HWDIM 64
#define PADW 66

static constexpr float CONV_COEF = 0.014731391274719739f; // 1/sqrt(9*512)
static constexpr float FC_COEF   = 0.044194173824159216f; // 1/sqrt(512)

typedef __bf16 bf16x8 __attribute__((ext_vector_type(8)));
typedef float  f32x4  __attribute__((ext_vector_type(4)));

typedef __attribute__((address_space(1))) void gvoid;
typedef __attribute__((address_space(3))) void lvoid;

__device__ __forceinline__ void async_cp16(const void* g, void* l) {
    __builtin_amdgcn_global_load_lds((gvoid*)g, (lvoid*)l, 16, 0, 0);
}

__device__ __forceinline__ ushort f2bf(float f) {
    union { float f; unsigned u; } un; un.f = f;
    unsigned u = un.u;
    return (ushort)((u + 0x7fffu + ((u >> 16) & 1u)) >> 16);
}

// zero only the halo ring of xs (replaces 71 MB memset with 4.3 MB of stores)
__global__ void k_halo(ushort* __restrict__ xs) {
    int b = blockIdx.y;
    int pidx = blockIdx.x * 4 + (threadIdx.x >> 6);  // 0..259 exactly (65*4)
    int ch = threadIdx.x & 63;
    int h, w;
    if (pidx < 66)       { h = 0;          w = pidx; }
    else if (pidx < 132) { h = 65;         w = pidx - 66; }
    else if (pidx < 196) { h = pidx - 131; w = 0; }
    else                 { h = pidx - 195; w = 65; }
    size_t base = (((size_t)(b * PADW + h)) * PADW + w) * IN_CH + ch * 8;
    uint4 z = {0u, 0u, 0u, 0u};
    *(uint4*)(xs + base) = z;
}

// s[b,i] = (wl[b,:]·fcw[:,i])*FC_COEF + fcb[i] + 1   — grid (B,4) x 128 thr
__global__ void k_style(const float* __restrict__ wl, const float* __restrict__ fcw,
                        const float* __restrict__ fcb, float* __restrict__ s) {
    int b = blockIdx.x;
    int i = blockIdx.y * 128 + threadIdx.x;
    __shared__ float lw[W_DIM];
    for (int j = threadIdx.x; j < W_DIM; j += 128) lw[j] = wl[b * W_DIM + j];
    __syncthreads();
    float acc = 0.f;
#pragma unroll 8
    for (int j = 0; j < W_DIM; ++j) acc += lw[j] * fcw[(size_t)j * IN_CH + i];
    s[b * IN_CH + i] = acc * FC_COEF + fcb[i] + 1.0f;
}

// xs[b][h+1][w+1][c] = bf16(x[b,h,w,c] * s[b,c])
__global__ void k_xs(const float* __restrict__ x, const float* __restrict__ s,
                     ushort* __restrict__ xs) {
    int t = blockIdx.x * blockDim.x + threadIdx.x;  // one float4 per thread
    int pix = t >> 7;
    int c = (t & 127) << 2;
    int b = pix >> 12;
    int hw = pix & 4095;
    int h = hw >> 6, w = hw & 63;
    float4 xv = ((const float4*)x)[t];
    float4 sv = ((const float4*)(s + b * IN_CH))[t & 127];
    ushort4 o;
    o.x = f2bf(xv.x * sv.x);
    o.y = f2bf(xv.y * sv.y);
    o.z = f2bf(xv.z * sv.z);
    o.w = f2bf(xv.w * sv.w);
    size_t dst = (((size_t)(b * PADW + h + 1)) * PADW + (w + 1)) * IN_CH + c;
    *(ushort4*)(xs + dst) = o;
}

// wT[kk][out][in] = bf16(w[kk][in][out])
__global__ void k_wt(const float* __restrict__ w, ushort* __restrict__ wT) {
    __shared__ float tile[32][33];
    int kk = blockIdx.z;
    const float* src = w + (size_t)kk * IN_CH * OUT_CH;
    ushort* dst = wT + (size_t)kk * IN_CH * OUT_CH;
    int i0 = blockIdx.y * 32;
    int o0 = blockIdx.x * 32;
    int tx = threadIdx.x, ty = threadIdx.y;
#pragma unroll
    for (int rr = 0; rr < 32; rr += 8)
        tile[ty + rr][tx] = src[(size_t)(i0 + ty + rr) * OUT_CH + o0 + tx];
    __syncthreads();
#pragma unroll
    for (int rr = 0; rr < 32; rr += 8)
        dst[(size_t)(o0 + ty + rr) * IN_CH + i0 + tx] = f2bf(tile[tx][ty + rr]);
}

// a2[in*512+out] = sum_kk w[kk][in][out]^2
__global__ void k_a2(const float* __restrict__ w, float* __restrict__ a2) {
    int n = blockIdx.x * blockDim.x + threadIdx.x;
    float sum = 0.f;
#pragma unroll
    for (int kk = 0; kk < 9; ++kk) {
        float v = w[(size_t)kk * (IN_CH * OUT_CH) + n];
        sum += v * v;
    }
    a2[n] = sum;
}

// dmod[b,o] = rsqrt(coef^2 * sum_in a2[in,o]*s[b,in]^2 + 1e-8) — grid (B,4) x 128
__global__ void k_dmod(const float* __restrict__ s, const float* __restrict__ a2,
                       float* __restrict__ dmod) {
    int b = blockIdx.x;
    int o = blockIdx.y * 128 + threadIdx.x;
    __shared__ float s2[IN_CH];
    for (int i = threadIdx.x; i < IN_CH; i += 128) {
        float v = s[b * IN_CH + i];
        s2[i] = v * v;
    }
    __syncthreads();
    float acc = 0.f;
#pragma unroll 8
    for (int i = 0; i < IN_CH; ++i) acc += s2[i] * a2[(size_t)i * OUT_CH + o];
    dmod[b * OUT_CH + o] = rsqrtf(acc * CONV_COEF * CONV_COEF + 1e-8f);
}

// Implicit-GEMM conv: M=65536 (b,h,w), N=512 (out), K=9*512.
// Block tile 128x128, BK=64 (32 MFMA per barrier-pair), 4 waves of 64x64.
__global__ __launch_bounds__(256) void k_conv(
    const ushort* __restrict__ xs, const ushort* __restrict__ wT,
    const float* __restrict__ dmod, const float* __restrict__ bias,
    float* __restrict__ out) {
    __shared__ ushort sA[128 * 64];
    __shared__ ushort sB[128 * 64];

    const int tid = threadIdx.x;
    const int wave = tid >> 6;
    const int lane = tid & 63;

    // XCD-grouped swizzle: 4 blocks sharing one A-tile (same mt) get equal
    // bid%8 (same XCD) and sit within one 32-block dispatch window.
    const int bid = blockIdx.x;
    const int mt = (bid & 7) | ((bid >> 5) << 3);
    const int nt = (bid >> 3) & 3;
    const int b  = mt >> 5;
    const int h0 = (mt & 31) << 1;
    const int n0 = nt << 7;

    // staging: slot s = i*256 + tid; row = i*32 + (tid>>3); phys chunk = tid&7;
    // logical k-chunk lc = (tid&7) ^ (row&7)  [bank swizzle, i-independent]
    const int srow = tid >> 3;
    const int lc   = (tid & 7) ^ (srow & 7);

    const ushort* gA[4];
    const ushort* gB[4];
#pragma unroll
    for (int i = 0; i < 4; ++i) {
        int row = i * 32 + srow;          // 0..127
        int rh  = row >> 6;
        int w   = row & 63;
        gA[i] = xs + (((size_t)(b * PADW + h0 + rh)) * PADW + w) * IN_CH + lc * 8;
        gB[i] = wT + ((size_t)(n0 + row)) * IN_CH + lc * 8;
    }
    ushort* dA[4];
    ushort* dB[4];
#pragma unroll
    for (int i = 0; i < 4; ++i) {
        dA[i] = sA + (i * 256 + wave * 64) * 8;  // wave-uniform, lane*16B implicit
        dB[i] = sB + (i * 256 + wave * 64) * 8;
    }

    const int r = lane & 15;
    const int q = lane >> 4;
    const int wr = (wave & 1) << 6;
    const int wc = (wave >> 1) << 6;

    // frag reads: addr = row*64 + pc*8, pc = (ksub*4+q) ^ (row&7) → 2-way=free
    const ushort* aRd[2][4];
    const ushort* bRd[2][4];
#pragma unroll
    for (int ks = 0; ks < 2; ++ks)
#pragma unroll
        for (int f = 0; f < 4; ++f) {
            int rowA = wr + f * 16 + r;
            aRd[ks][f] = sA + rowA * 64 + ((ks * 4 + q) ^ (rowA & 7)) * 8;
            int rowB = wc + f * 16 + r;
            bRd[ks][f] = sB + rowB * 64 + ((ks * 4 + q) ^ (rowB & 7)) * 8;
        }

    f32x4 acc[4][4];
#pragma unroll
    for (int i = 0; i < 4; ++i)
#pragma unroll
        for (int j = 0; j < 4; ++j) {
            f32x4 z = {0.f, 0.f, 0.f, 0.f};
            acc[i][j] = z;
        }

    for (int kk = 0; kk < 9; ++kk) {
        const int aoff = ((kk / 3) * PADW + (kk % 3)) * IN_CH;
        const size_t boff = (size_t)kk * (IN_CH * OUT_CH);
        for (int c0 = 0; c0 < IN_CH; c0 += 64) {
            __syncthreads();   // prev compute done before LDS overwrite
#pragma unroll
            for (int i = 0; i < 4; ++i) {
                async_cp16(gA[i] + aoff + c0, dA[i]);
                async_cp16(gB[i] + boff + c0, dB[i]);
            }
            __syncthreads();   // drains vmcnt → staged data visible
#pragma unroll
            for (int ks = 0; ks < 2; ++ks) {
                bf16x8 av[4], bv[4];
#pragma unroll
                for (int f = 0; f < 4; ++f) av[f] = *(const bf16x8*)aRd[ks][f];
#pragma unroll
                for (int f = 0; f < 4; ++f) bv[f] = *(const bf16x8*)bRd[ks][f];
#pragma unroll
                for (int i = 0; i < 4; ++i)
#pragma unroll
                    for (int j = 0; j < 4; ++j)
                        acc[i][j] = __builtin_amdgcn_mfma_f32_16x16x32_bf16(
                            av[i], bv[j], acc[i][j], 0, 0, 0);
            }
        }
    }

    // epilogue: C/D layout col=lane&15 (n), row=(lane>>4)*4+reg (m)
#pragma unroll
    for (int j = 0; j < 4; ++j) {
        const int n = n0 + wc + j * 16 + r;
        const float scale = dmod[b * OUT_CH + n] * CONV_COEF;
        const float bv2 = bias[n];
#pragma unroll
        for (int i = 0; i < 4; ++i) {
#pragma unroll
            for (int e = 0; e < 4; ++e) {
                const int m = wr + i * 16 + q * 4 + e;
                const int h = h0 + (m >> 6);
                const int w = m & 63;
                out[(((size_t)(b * HWDIM + h)) * HWDIM + w) * OUT_CH + n] =
                    acc[i][j][e] * scale + bv2;
            }
        }
    }
}

extern "C" void kernel_launch(void* const* d_in, const int* in_sizes, int n_in,
                              void* d_out, int out_size, void* d_ws, size_t ws_size,
                              hipStream_t stream) {
    const float* x    = (const float*)d_in[0];
    const float* wl   = (const float*)d_in[1];
    const float* w    = (const float*)d_in[2];
    const float* bias = (const float*)d_in[3];
    const float* fcw  = (const float*)d_in[4];
    const float* fcb  = (const float*)d_in[5];
    float* out = (float*)d_out;

    char* ws = (char*)d_ws;
    const size_t XS_BYTES = (size_t)BATCH * PADW * PADW * IN_CH * 2;  // 71,368,704
    const size_t WT_BYTES = (size_t)9 * IN_CH * OUT_CH * 2;           //  4,718,592
    ushort* xs   = (ushort*)ws;
    ushort* wT   = (ushort*)(ws + XS_BYTES);
    float*  s    = (float*)(ws + XS_BYTES + WT_BYTES);
    float*  dmod = s + BATCH * IN_CH;
    float*  a2   = dmod + BATCH * OUT_CH;

    k_halo<<<dim3(65, BATCH), 256, 0, stream>>>(xs);
    k_style<<<dim3(BATCH, 4), 128, 0, stream>>>(wl, fcw, fcb, s);
    k_xs<<<(BATCH * HWDIM * HWDIM * IN_CH / 4) / 256, 256, 0, stream>>>(x, s, xs);
    k_wt<<<dim3(16, 16, 9), dim3(32, 8), 0, stream>>>(w, wT);
    k_a2<<<(IN_CH * OUT_CH) / 256, 256, 0, stream>>>(w, a2);
    k_dmod<<<dim3(BATCH, 4), 128, 0, stream>>>(s, a2, dmod);
    k_conv<<<2048, 256, 0, stream>>>(xs, wT, dmod, bias, out);
}